// Round 6
// baseline (400.654 us; speedup 1.0000x reference)
//
#include <hip/hip_runtime.h>

#define F 64
typedef unsigned int u32;

#define SCAN_BLOCK 1024
#define SCAN_ITEMS 4   // elements per thread -> 4096 per block

// ---- bf16x2 pack/unpack (RNE) ----------------------------------------------
__device__ __forceinline__ u32 pack_bf16x2(float lo, float hi) {
    u32 a = __float_as_uint(lo);
    u32 b = __float_as_uint(hi);
    a = (a + 0x7fffu + ((a >> 16) & 1u)) >> 16;
    b = (b + 0x7fffu + ((b >> 16) & 1u)) >> 16;
    return a | (b << 16);
}
__device__ __forceinline__ float unpack_lo(u32 p) { return __uint_as_float(p << 16); }
__device__ __forceinline__ float unpack_hi(u32 p) { return __uint_as_float(p & 0xffff0000u); }

// ---------------------------------------------------------------------------
// k_gemm: even/odd block task split to keep VGPR pressure low.
//   task 0 (even blocks): initp[n][f] = pack_bf16(x_r@W0+b, x_i@W0+b) -> d_out
//   task 1 (odd  blocks): x1p[n][f]   = pack_bf16(x_r@W1,   x_i@W1)   -> ws
// One wave per node; lane = output feature; one 64-reg W column set per block.
// __launch_bounds__(256,4): cap VGPR at 128 -> 4 waves/SIMD.
// ---------------------------------------------------------------------------
__global__ __launch_bounds__(256, 4) void k_gemm(
    const float* __restrict__ x_real, const float* __restrict__ x_imag,
    const float* __restrict__ weight, const float* __restrict__ bias,
    u32* __restrict__ x1p, u32* __restrict__ initp, int n_nodes)
{
    const int task = blockIdx.x & 1;
    const int lane = threadIdx.x & 63;
    const int wId = ((blockIdx.x >> 1) << 2) + (threadIdx.x >> 6);  // wave within task
    const int nW = (gridDim.x >> 1) << 2;

    const float* __restrict__ W = weight + task * F * F;
    float wc[F];
#pragma unroll
    for (int k = 0; k < F; ++k) wc[k] = W[k * F + lane];
    const float bf = task ? 0.f : bias[lane];
    u32* __restrict__ dst = task ? x1p : initp;

    for (int n = wId; n < n_nodes; n += nW) {
        const int nu = __builtin_amdgcn_readfirstlane(n);
        const float4* __restrict__ xr4 = (const float4*)(x_real + (size_t)nu * F);
        const float4* __restrict__ xi4 = (const float4*)(x_imag + (size_t)nu * F);

        float aR0 = 0.f, aI0 = 0.f, aR1 = 0.f, aI1 = 0.f;
#pragma unroll
        for (int q = 0; q < 4; ++q) {
            float4 r[4], im[4];
#pragma unroll
            for (int j = 0; j < 4; ++j) {
                r[j]  = xr4[q * 4 + j];
                im[j] = xi4[q * 4 + j];
            }
#pragma unroll
            for (int j = 0; j < 4; ++j) {
                const int k = q * 16 + j * 4;
                aR0 = fmaf(r[j].x,  wc[k],     aR0);
                aR1 = fmaf(r[j].y,  wc[k + 1], aR1);
                aR0 = fmaf(r[j].z,  wc[k + 2], aR0);
                aR1 = fmaf(r[j].w,  wc[k + 3], aR1);
                aI0 = fmaf(im[j].x, wc[k],     aI0);
                aI1 = fmaf(im[j].y, wc[k + 1], aI1);
                aI0 = fmaf(im[j].z, wc[k + 2], aI0);
                aI1 = fmaf(im[j].w, wc[k + 3], aI1);
            }
        }
        dst[(size_t)nu * F + lane] = pack_bf16x2(aR0 + aR1 + bf, aI0 + aI1 + bf);
    }
}

// ---------------------------------------------------------------------------
// CSR build
// ---------------------------------------------------------------------------
__global__ void k_hist(const int* __restrict__ src, int* __restrict__ counts, int n_edges) {
    int e = blockIdx.x * 256 + threadIdx.x;
    if (e < n_edges) atomicAdd(&counts[src[e]], 1);
}

__global__ __launch_bounds__(1024) void k_scan1(
    const int* __restrict__ cnt, int* __restrict__ pre,
    int* __restrict__ partials, int n)
{
    __shared__ int wsum[16];
    const int t = threadIdx.x;
    const int lane = t & 63, wid = t >> 6;
    const int base = blockIdx.x * (SCAN_BLOCK * SCAN_ITEMS) + t * SCAN_ITEMS;

    int v[SCAN_ITEMS];
    int local = 0;
#pragma unroll
    for (int j = 0; j < SCAN_ITEMS; ++j) {
        const int idx = base + j;
        const int c = (idx < n) ? cnt[idx] : 0;
        v[j] = local;
        local += c;
    }
    int incl = local;
#pragma unroll
    for (int d = 1; d < 64; d <<= 1) {
        int x = __shfl_up(incl, d);
        if (lane >= d) incl += x;
    }
    if (lane == 63) wsum[wid] = incl;
    __syncthreads();
    if (wid == 0) {
        int s = (lane < 16) ? wsum[lane] : 0;
#pragma unroll
        for (int d = 1; d < 16; d <<= 1) {
            int x = __shfl_up(s, d);
            if (lane >= d) s += x;
        }
        if (lane < 16) wsum[lane] = s;
    }
    __syncthreads();
    const int texcl = (incl - local) + (wid ? wsum[wid - 1] : 0);
#pragma unroll
    for (int j = 0; j < SCAN_ITEMS; ++j) {
        const int idx = base + j;
        if (idx < n) pre[idx] = texcl + v[j];
    }
    if (t == SCAN_BLOCK - 1) partials[blockIdx.x] = texcl + local;
}

__global__ __launch_bounds__(1024) void k_scan2(
    int* __restrict__ pre, const int* __restrict__ partials,
    int* __restrict__ cursor, int n, int n_edges)
{
    __shared__ int s_off;
    const int t = threadIdx.x;
    if (t < 64) {
        int val = (t < blockIdx.x) ? partials[t] : 0;
#pragma unroll
        for (int d = 32; d > 0; d >>= 1) val += __shfl_down(val, d);
        if (t == 0) s_off = val;
    }
    __syncthreads();
    const int boff = s_off;
    const int base = blockIdx.x * (SCAN_BLOCK * SCAN_ITEMS) + t * SCAN_ITEMS;
#pragma unroll
    for (int j = 0; j < SCAN_ITEMS; ++j) {
        const int idx = base + j;
        if (idx < n) {
            const int o = boff + pre[idx];
            pre[idx] = o;
            cursor[idx] = o;
        }
    }
    if (blockIdx.x == 0 && t == 0) pre[n] = n_edges;
}

__global__ void k_place(const int* __restrict__ edge_index,
                        const float* __restrict__ nr, const float* __restrict__ ni,
                        int* __restrict__ cursor, int2* __restrict__ meta2, int n_edges) {
    int e = blockIdx.x * 256 + threadIdx.x;
    if (e >= n_edges) return;
    const int s = edge_index[e];
    const int pos = atomicAdd(&cursor[s], 1);
    int2 m;
    m.x = edge_index[n_edges + e];
    m.y = (int)pack_bf16x2(nr[e], ni[e]);
    meta2[pos] = m;
}

// ---------------------------------------------------------------------------
// Gather: one wave per node. Pure {meta -> gather -> FMA}; init from initp.
// ---------------------------------------------------------------------------
#define APPLY2(m, p, aR, aI)                                  \
    do {                                                      \
        const float cr = unpack_lo((u32)(m).y);               \
        const float ci = unpack_hi((u32)(m).y);               \
        const float xr = unpack_lo(p);                        \
        const float xi = unpack_hi(p);                        \
        aR = fmaf(cr, xr, fmaf(-ci, xi, aR));                 \
        aI = fmaf(cr, xi, fmaf(ci, xr, aI));                  \
    } while (0)

__global__ __launch_bounds__(256) void k_gather(
    const u32* __restrict__ x1p, const u32* __restrict__ initp,
    const int* __restrict__ offsets, const int2* __restrict__ meta2,
    float* __restrict__ out_real, float* __restrict__ out_imag,
    int n_nodes)
{
    const int lane = threadIdx.x & 63;
    const int w = (blockIdx.x * blockDim.x + threadIdx.x) >> 6;
    const int nw = (gridDim.x * blockDim.x) >> 6;

    for (int n = w; n < n_nodes; n += nw) {
        const int nu = __builtin_amdgcn_readfirstlane(n);
        const int beg = __builtin_amdgcn_readfirstlane(offsets[nu]);
        const int end = __builtin_amdgcn_readfirstlane(offsets[nu + 1]);

        float aR0 = 0.f, aI0 = 0.f, aR1 = 0.f, aI1 = 0.f;
        float aR2 = 0.f, aI2 = 0.f, aR3 = 0.f, aI3 = 0.f;

        int e = beg;
        for (; e + 8 <= end; e += 8) {
            const int2 m0 = meta2[e + 0];
            const int2 m1 = meta2[e + 1];
            const int2 m2 = meta2[e + 2];
            const int2 m3 = meta2[e + 3];
            const int2 m4 = meta2[e + 4];
            const int2 m5 = meta2[e + 5];
            const int2 m6 = meta2[e + 6];
            const int2 m7 = meta2[e + 7];
            const u32 p0 = x1p[(size_t)m0.x * F + lane];
            const u32 p1 = x1p[(size_t)m1.x * F + lane];
            const u32 p2 = x1p[(size_t)m2.x * F + lane];
            const u32 p3 = x1p[(size_t)m3.x * F + lane];
            const u32 p4 = x1p[(size_t)m4.x * F + lane];
            const u32 p5 = x1p[(size_t)m5.x * F + lane];
            const u32 p6 = x1p[(size_t)m6.x * F + lane];
            const u32 p7 = x1p[(size_t)m7.x * F + lane];
            APPLY2(m0, p0, aR0, aI0);
            APPLY2(m1, p1, aR1, aI1);
            APPLY2(m2, p2, aR2, aI2);
            APPLY2(m3, p3, aR3, aI3);
            APPLY2(m4, p4, aR0, aI0);
            APPLY2(m5, p5, aR1, aI1);
            APPLY2(m6, p6, aR2, aI2);
            APPLY2(m7, p7, aR3, aI3);
        }
        for (; e + 4 <= end; e += 4) {
            const int2 m0 = meta2[e + 0];
            const int2 m1 = meta2[e + 1];
            const int2 m2 = meta2[e + 2];
            const int2 m3 = meta2[e + 3];
            const u32 p0 = x1p[(size_t)m0.x * F + lane];
            const u32 p1 = x1p[(size_t)m1.x * F + lane];
            const u32 p2 = x1p[(size_t)m2.x * F + lane];
            const u32 p3 = x1p[(size_t)m3.x * F + lane];
            APPLY2(m0, p0, aR0, aI0);
            APPLY2(m1, p1, aR1, aI1);
            APPLY2(m2, p2, aR2, aI2);
            APPLY2(m3, p3, aR3, aI3);
        }
        for (; e < end; ++e) {
            const int2 m = meta2[e];
            const u32 p = x1p[(size_t)m.x * F + lane];
            APPLY2(m, p, aR0, aI0);
        }

        const size_t b = (size_t)nu * F + lane;
        const u32 iw = initp[b];   // aliases out_real[b]; read-before-write, same thread
        const float oR = unpack_lo(iw) + ((aR0 + aR1) + (aR2 + aR3));
        const float oI = unpack_hi(iw) + ((aI0 + aI1) + (aI2 + aI3));
        __builtin_nontemporal_store(oR, &out_real[b]);
        __builtin_nontemporal_store(oI, &out_imag[b]);
    }
}

// ---------------------------------------------------------------------------
// Fallback (ws too small): f32 init + atomic scatter from packed x1.
// ---------------------------------------------------------------------------
__global__ __launch_bounds__(256) void k_init_out(
    const float* __restrict__ x_real, const float* __restrict__ x_imag,
    const float* __restrict__ weight, const float* __restrict__ bias,
    float* __restrict__ out_real, float* __restrict__ out_imag, int n_nodes)
{
    const int lane = threadIdx.x & 63;
    const int waveId = (blockIdx.x * blockDim.x + threadIdx.x) >> 6;
    const int nWaves = (gridDim.x * blockDim.x) >> 6;
    const float* __restrict__ W0 = weight;
    float w0c[F];
#pragma unroll
    for (int k = 0; k < F; ++k) w0c[k] = W0[k * F + lane];
    const float bf = bias[lane];
    for (int n = waveId; n < n_nodes; n += nWaves) {
        const int nu = __builtin_amdgcn_readfirstlane(n);
        const float4* __restrict__ xr4 = (const float4*)(x_real + (size_t)nu * F);
        const float4* __restrict__ xi4 = (const float4*)(x_imag + (size_t)nu * F);
        float gR = 0.f, gI = 0.f;
#pragma unroll
        for (int k4 = 0; k4 < F / 4; ++k4) {
            const float4 vr = xr4[k4];
            const float4 vi = xi4[k4];
            const float xr[4] = {vr.x, vr.y, vr.z, vr.w};
            const float xi[4] = {vi.x, vi.y, vi.z, vi.w};
#pragma unroll
            for (int j = 0; j < 4; ++j) {
                const int k = 4 * k4 + j;
                gR = fmaf(xr[j], w0c[k], gR);
                gI = fmaf(xi[j], w0c[k], gI);
            }
        }
        const size_t b = (size_t)nu * F + lane;
        out_real[b] = gR + bf;
        out_imag[b] = gI + bf;
    }
}

__global__ __launch_bounds__(256) void k_x1_only(
    const float* __restrict__ x_real, const float* __restrict__ x_imag,
    const float* __restrict__ weight, u32* __restrict__ x1p, int n_nodes)
{
    const int lane = threadIdx.x & 63;
    const int waveId = (blockIdx.x * blockDim.x + threadIdx.x) >> 6;
    const int nWaves = (gridDim.x * blockDim.x) >> 6;
    const float* __restrict__ W1 = weight + F * F;
    float w1c[F];
#pragma unroll
    for (int k = 0; k < F; ++k) w1c[k] = W1[k * F + lane];
    for (int n = waveId; n < n_nodes; n += nWaves) {
        const int nu = __builtin_amdgcn_readfirstlane(n);
        const float4* __restrict__ xr4 = (const float4*)(x_real + (size_t)nu * F);
        const float4* __restrict__ xi4 = (const float4*)(x_imag + (size_t)nu * F);
        float aR = 0.f, aI = 0.f;
#pragma unroll
        for (int k4 = 0; k4 < F / 4; ++k4) {
            const float4 vr = xr4[k4];
            const float4 vi = xi4[k4];
            const float xr[4] = {vr.x, vr.y, vr.z, vr.w};
            const float xi[4] = {vi.x, vi.y, vi.z, vi.w};
#pragma unroll
            for (int j = 0; j < 4; ++j) {
                const int k = 4 * k4 + j;
                aR = fmaf(xr[j], w1c[k], aR);
                aI = fmaf(xi[j], w1c[k], aI);
            }
        }
        x1p[(size_t)nu * F + lane] = pack_bf16x2(aR, aI);
    }
}

__global__ __launch_bounds__(256) void k_scatter(
    const u32* __restrict__ x1p, const int* __restrict__ edge_index,
    const float* __restrict__ norm_real, const float* __restrict__ norm_imag,
    float* __restrict__ out_real, float* __restrict__ out_imag, int n_edges)
{
    const long long gid = (long long)blockIdx.x * blockDim.x + threadIdx.x;
    const long long total = (long long)n_edges * 16;
    if (gid >= total) return;
    const int e = (int)(gid >> 4);
    const int c = (int)(gid & 15);
    const int s = edge_index[e];
    const int d = edge_index[n_edges + e];
    const float cr = norm_real[e];
    const float ci = norm_imag[e];
    const uint4 p4 = *(const uint4*)(x1p + (size_t)d * F + c * 4);
    const u32 pp[4] = {p4.x, p4.y, p4.z, p4.w};
    float* __restrict__ pr = out_real + (size_t)s * F + c * 4;
    float* __restrict__ pi = out_imag + (size_t)s * F + c * 4;
#pragma unroll
    for (int j = 0; j < 4; ++j) {
        const float xr = unpack_lo(pp[j]);
        const float xi = unpack_hi(pp[j]);
        unsafeAtomicAdd(pr + j, fmaf(cr, xr, -ci * xi));
        unsafeAtomicAdd(pi + j, fmaf(cr, xi, ci * xr));
    }
}

extern "C" void kernel_launch(void* const* d_in, const int* in_sizes, int n_in,
                              void* d_out, int out_size, void* d_ws, size_t ws_size,
                              hipStream_t stream) {
    const float* x_real     = (const float*)d_in[0];
    const float* x_imag     = (const float*)d_in[1];
    const float* weight     = (const float*)d_in[2];
    const float* bias       = (const float*)d_in[3];
    const float* norm_real  = (const float*)d_in[4];
    const float* norm_imag  = (const float*)d_in[5];
    const int*   edge_index = (const int*)d_in[6];

    const int n_nodes = in_sizes[0] / F;
    const int n_edges = in_sizes[4];

    float* out_real = (float*)d_out;
    float* out_imag = out_real + (size_t)n_nodes * F;
    u32*   initp    = (u32*)d_out;   // packed bf16 init, overwritten by gather

    // ws layout: [x1p][meta2][offsets][cursor][partials]
    char* ws = (char*)d_ws;
    const size_t x1_bytes   = (size_t)n_nodes * F * sizeof(u32);   // 25.6 MB
    const size_t meta_bytes = (size_t)n_edges * sizeof(int2);      // 12.8 MB
    const size_t off_bytes  = (size_t)(n_nodes + 1) * sizeof(int);
    const size_t cur_bytes  = (size_t)n_nodes * sizeof(int);
    const size_t par_bytes  = 64 * sizeof(int);
    const size_t need = x1_bytes + meta_bytes + off_bytes + cur_bytes + par_bytes;

    u32*  x1p      = (u32*)ws;
    int2* meta2    = (int2*)(ws + x1_bytes);
    int*  offsets  = (int*)(ws + x1_bytes + meta_bytes);
    int*  cursor   = (int*)(ws + x1_bytes + meta_bytes + off_bytes);
    int*  partials = (int*)(ws + x1_bytes + meta_bytes + off_bytes + cur_bytes);

    const int eblocks = (n_edges + 255) / 256;

    if (ws_size >= need) {
        hipMemsetAsync(cursor, 0, cur_bytes, stream);
        k_gemm<<<4096, 256, 0, stream>>>(
            x_real, x_imag, weight, bias, x1p, initp, n_nodes);
        k_hist<<<eblocks, 256, 0, stream>>>(edge_index, cursor, n_edges);
        const int sblocks = (n_nodes + SCAN_BLOCK * SCAN_ITEMS - 1) / (SCAN_BLOCK * SCAN_ITEMS);
        k_scan1<<<sblocks, SCAN_BLOCK, 0, stream>>>(cursor, offsets, partials, n_nodes);
        k_scan2<<<sblocks, SCAN_BLOCK, 0, stream>>>(offsets, partials, cursor, n_nodes, n_edges);
        k_place<<<eblocks, 256, 0, stream>>>(edge_index, norm_real, norm_imag,
                                             cursor, meta2, n_edges);
        k_gather<<<2048, 256, 0, stream>>>(
            x1p, initp, offsets, meta2, out_real, out_imag, n_nodes);
    } else {
        k_init_out<<<2048, 256, 0, stream>>>(
            x_real, x_imag, weight, bias, out_real, out_imag, n_nodes);
        k_x1_only<<<2048, 256, 0, stream>>>(x_real, x_imag, weight, x1p, n_nodes);
        const long long work = (long long)n_edges * 16;
        const int blocks = (int)((work + 255) / 256);
        k_scatter<<<blocks, 256, 0, stream>>>(
            x1p, edge_index, norm_real, norm_imag, out_real, out_imag, n_edges);
    }
}

// Round 7
// 307.703 us; speedup vs baseline: 1.3021x; 1.3021x over previous
//
#include <hip/hip_runtime.h>

#define F 64
typedef unsigned int u32;
typedef float f8 __attribute__((ext_vector_type(8)));

#define SCAN_BLOCK 1024
#define SCAN_ITEMS 4   // elements per thread -> 4096 per block

// ---- bf16x2 pack/unpack (RNE) ----------------------------------------------
__device__ __forceinline__ u32 pack_bf16x2(float lo, float hi) {
    u32 a = __float_as_uint(lo);
    u32 b = __float_as_uint(hi);
    a = (a + 0x7fffu + ((a >> 16) & 1u)) >> 16;
    b = (b + 0x7fffu + ((b >> 16) & 1u)) >> 16;
    return a | (b << 16);
}
__device__ __forceinline__ float unpack_lo(u32 p) { return __uint_as_float(p << 16); }
__device__ __forceinline__ float unpack_hi(u32 p) { return __uint_as_float(p & 0xffff0000u); }

// ---------------------------------------------------------------------------
// k_gemm: LDS-tiled, n-parallel. One block = 64-node tile.
//   Stage x_real/x_imag tile -> LDS (coalesced float4, stride-65 pad).
//   lane = node, wave w covers features [16w,16w+16). W from SGPRs (uniform).
//   initp[n][f] = pack_bf16(x_r@W0+b, x_i@W0+b)   -> d_out region
//   x1p[n][f]   = pack_bf16(x_r@W1,   x_i@W1)     -> ws
// ---------------------------------------------------------------------------
__global__ __launch_bounds__(256, 4) void k_gemm(
    const float* __restrict__ x_real, const float* __restrict__ x_imag,
    const float* __restrict__ weight, const float* __restrict__ bias,
    u32* __restrict__ x1p, u32* __restrict__ initp, int n_nodes)
{
    __shared__ float xs[2][64 * 65];   // stride 65: conflict-free r/w

    const int t = threadIdx.x;
    const int base_node = blockIdx.x * 64;

    // ---- stage: 8 float4 per thread, coalesced ----
#pragma unroll
    for (int c = 0; c < 8; ++c) {
        const int fq  = t + 256 * c;       // 0..2047 float4 slots
        const int arr = fq >> 10;          // 0: real, 1: imag
        const int rem = fq & 1023;
        const int n   = rem >> 4;
        const int c4  = rem & 15;
        const int g   = base_node + n;
        const float* __restrict__ s = arr ? x_imag : x_real;
        float4 v = make_float4(0.f, 0.f, 0.f, 0.f);
        if (g < n_nodes) v = *(const float4*)(s + (size_t)g * F + c4 * 4);
        float* d = &xs[arr][n * 65 + c4 * 4];
        d[0] = v.x; d[1] = v.y; d[2] = v.z; d[3] = v.w;
    }
    __syncthreads();

    // ---- compute ----
    const int lane = t & 63;
    const int f0 = __builtin_amdgcn_readfirstlane((t >> 6) * 16);
    const int g = base_node + lane;

    const float* __restrict__ W0 = weight;
    const float* __restrict__ W1 = weight + F * F;

    float aR0[16], aI0[16], aR1[16], aI1[16];
#pragma unroll
    for (int j = 0; j < 16; ++j) { aR0[j] = 0.f; aI0[j] = 0.f; aR1[j] = 0.f; aI1[j] = 0.f; }

    const float* __restrict__ xrow_r = &xs[0][lane * 65];
    const float* __restrict__ xrow_i = &xs[1][lane * 65];

    for (int k0 = 0; k0 < F; k0 += 4) {
#pragma unroll
        for (int kk = 0; kk < 4; ++kk) {
            const int k = k0 + kk;
            const float xr = xrow_r[k];
            const float xi = xrow_i[k];
            const f8 wa0 = *(const f8*)(W0 + k * F + f0);      // uniform -> s_load
            const f8 wb0 = *(const f8*)(W0 + k * F + f0 + 8);
            const f8 wa1 = *(const f8*)(W1 + k * F + f0);
            const f8 wb1 = *(const f8*)(W1 + k * F + f0 + 8);
#pragma unroll
            for (int j = 0; j < 8; ++j) {
                aR0[j]     = fmaf(xr, wa0[j], aR0[j]);
                aI0[j]     = fmaf(xi, wa0[j], aI0[j]);
                aR1[j]     = fmaf(xr, wa1[j], aR1[j]);
                aI1[j]     = fmaf(xi, wa1[j], aI1[j]);
                aR0[8 + j] = fmaf(xr, wb0[j], aR0[8 + j]);
                aI0[8 + j] = fmaf(xi, wb0[j], aI0[8 + j]);
                aR1[8 + j] = fmaf(xr, wb1[j], aR1[8 + j]);
                aI1[8 + j] = fmaf(xi, wb1[j], aI1[8 + j]);
            }
        }
    }

    if (g < n_nodes) {
        const f8 b0 = *(const f8*)(bias + f0);
        const f8 b1 = *(const f8*)(bias + f0 + 8);
        u32 pi[16], pw[16];
#pragma unroll
        for (int j = 0; j < 8; ++j) {
            pi[j]     = pack_bf16x2(aR0[j] + b0[j],     aI0[j] + b0[j]);
            pi[8 + j] = pack_bf16x2(aR0[8 + j] + b1[j], aI0[8 + j] + b1[j]);
            pw[j]     = pack_bf16x2(aR1[j],     aI1[j]);
            pw[8 + j] = pack_bf16x2(aR1[8 + j], aI1[8 + j]);
        }
        uint4* __restrict__ di = (uint4*)(initp + (size_t)g * F + f0);
        uint4* __restrict__ dw = (uint4*)(x1p  + (size_t)g * F + f0);
#pragma unroll
        for (int q = 0; q < 4; ++q) {
            di[q] = make_uint4(pi[4 * q], pi[4 * q + 1], pi[4 * q + 2], pi[4 * q + 3]);
            dw[q] = make_uint4(pw[4 * q], pw[4 * q + 1], pw[4 * q + 2], pw[4 * q + 3]);
        }
    }
}

// ---------------------------------------------------------------------------
// CSR build
// ---------------------------------------------------------------------------
__global__ void k_hist(const int* __restrict__ src, int* __restrict__ counts, int n_edges) {
    int e = blockIdx.x * 256 + threadIdx.x;
    if (e < n_edges) atomicAdd(&counts[src[e]], 1);
}

__global__ __launch_bounds__(1024) void k_scan1(
    const int* __restrict__ cnt, int* __restrict__ pre,
    int* __restrict__ partials, int n)
{
    __shared__ int wsum[16];
    const int t = threadIdx.x;
    const int lane = t & 63, wid = t >> 6;
    const int base = blockIdx.x * (SCAN_BLOCK * SCAN_ITEMS) + t * SCAN_ITEMS;

    int v[SCAN_ITEMS];
    int local = 0;
#pragma unroll
    for (int j = 0; j < SCAN_ITEMS; ++j) {
        const int idx = base + j;
        const int c = (idx < n) ? cnt[idx] : 0;
        v[j] = local;
        local += c;
    }
    int incl = local;
#pragma unroll
    for (int d = 1; d < 64; d <<= 1) {
        int x = __shfl_up(incl, d);
        if (lane >= d) incl += x;
    }
    if (lane == 63) wsum[wid] = incl;
    __syncthreads();
    if (wid == 0) {
        int s = (lane < 16) ? wsum[lane] : 0;
#pragma unroll
        for (int d = 1; d < 16; d <<= 1) {
            int x = __shfl_up(s, d);
            if (lane >= d) s += x;
        }
        if (lane < 16) wsum[lane] = s;
    }
    __syncthreads();
    const int texcl = (incl - local) + (wid ? wsum[wid - 1] : 0);
#pragma unroll
    for (int j = 0; j < SCAN_ITEMS; ++j) {
        const int idx = base + j;
        if (idx < n) pre[idx] = texcl + v[j];
    }
    if (t == SCAN_BLOCK - 1) partials[blockIdx.x] = texcl + local;
}

__global__ __launch_bounds__(1024) void k_scan2(
    int* __restrict__ pre, const int* __restrict__ partials,
    int* __restrict__ cursor, int n, int n_edges)
{
    __shared__ int s_off;
    const int t = threadIdx.x;
    if (t < 64) {
        int val = (t < blockIdx.x) ? partials[t] : 0;
#pragma unroll
        for (int d = 32; d > 0; d >>= 1) val += __shfl_down(val, d);
        if (t == 0) s_off = val;
    }
    __syncthreads();
    const int boff = s_off;
    const int base = blockIdx.x * (SCAN_BLOCK * SCAN_ITEMS) + t * SCAN_ITEMS;
#pragma unroll
    for (int j = 0; j < SCAN_ITEMS; ++j) {
        const int idx = base + j;
        if (idx < n) {
            const int o = boff + pre[idx];
            pre[idx] = o;
            cursor[idx] = o;
        }
    }
    if (blockIdx.x == 0 && t == 0) pre[n] = n_edges;
}

__global__ void k_place(const int* __restrict__ edge_index,
                        const float* __restrict__ nr, const float* __restrict__ ni,
                        int* __restrict__ cursor, int2* __restrict__ meta2, int n_edges) {
    int e = blockIdx.x * 256 + threadIdx.x;
    if (e >= n_edges) return;
    const int s = edge_index[e];
    const int pos = atomicAdd(&cursor[s], 1);
    int2 m;
    m.x = edge_index[n_edges + e];
    m.y = (int)pack_bf16x2(nr[e], ni[e]);
    meta2[pos] = m;
}

// ---------------------------------------------------------------------------
// Gather: one wave per node. Pure {meta -> gather -> FMA}; init from initp.
// ---------------------------------------------------------------------------
#define APPLY2(m, p, aR, aI)                                  \
    do {                                                      \
        const float cr = unpack_lo((u32)(m).y);               \
        const float ci = unpack_hi((u32)(m).y);               \
        const float xr = unpack_lo(p);                        \
        const float xi = unpack_hi(p);                        \
        aR = fmaf(cr, xr, fmaf(-ci, xi, aR));                 \
        aI = fmaf(cr, xi, fmaf(ci, xr, aI));                  \
    } while (0)

__global__ __launch_bounds__(256) void k_gather(
    const u32* __restrict__ x1p, const u32* __restrict__ initp,
    const int* __restrict__ offsets, const int2* __restrict__ meta2,
    float* __restrict__ out_real, float* __restrict__ out_imag,
    int n_nodes)
{
    const int lane = threadIdx.x & 63;
    const int w = (blockIdx.x * blockDim.x + threadIdx.x) >> 6;
    const int nw = (gridDim.x * blockDim.x) >> 6;

    for (int n = w; n < n_nodes; n += nw) {
        const int nu = __builtin_amdgcn_readfirstlane(n);
        const int beg = __builtin_amdgcn_readfirstlane(offsets[nu]);
        const int end = __builtin_amdgcn_readfirstlane(offsets[nu + 1]);

        float aR0 = 0.f, aI0 = 0.f, aR1 = 0.f, aI1 = 0.f;
        float aR2 = 0.f, aI2 = 0.f, aR3 = 0.f, aI3 = 0.f;

        int e = beg;
        for (; e + 8 <= end; e += 8) {
            const int2 m0 = meta2[e + 0];
            const int2 m1 = meta2[e + 1];
            const int2 m2 = meta2[e + 2];
            const int2 m3 = meta2[e + 3];
            const int2 m4 = meta2[e + 4];
            const int2 m5 = meta2[e + 5];
            const int2 m6 = meta2[e + 6];
            const int2 m7 = meta2[e + 7];
            const u32 p0 = x1p[(size_t)m0.x * F + lane];
            const u32 p1 = x1p[(size_t)m1.x * F + lane];
            const u32 p2 = x1p[(size_t)m2.x * F + lane];
            const u32 p3 = x1p[(size_t)m3.x * F + lane];
            const u32 p4 = x1p[(size_t)m4.x * F + lane];
            const u32 p5 = x1p[(size_t)m5.x * F + lane];
            const u32 p6 = x1p[(size_t)m6.x * F + lane];
            const u32 p7 = x1p[(size_t)m7.x * F + lane];
            APPLY2(m0, p0, aR0, aI0);
            APPLY2(m1, p1, aR1, aI1);
            APPLY2(m2, p2, aR2, aI2);
            APPLY2(m3, p3, aR3, aI3);
            APPLY2(m4, p4, aR0, aI0);
            APPLY2(m5, p5, aR1, aI1);
            APPLY2(m6, p6, aR2, aI2);
            APPLY2(m7, p7, aR3, aI3);
        }
        for (; e + 4 <= end; e += 4) {
            const int2 m0 = meta2[e + 0];
            const int2 m1 = meta2[e + 1];
            const int2 m2 = meta2[e + 2];
            const int2 m3 = meta2[e + 3];
            const u32 p0 = x1p[(size_t)m0.x * F + lane];
            const u32 p1 = x1p[(size_t)m1.x * F + lane];
            const u32 p2 = x1p[(size_t)m2.x * F + lane];
            const u32 p3 = x1p[(size_t)m3.x * F + lane];
            APPLY2(m0, p0, aR0, aI0);
            APPLY2(m1, p1, aR1, aI1);
            APPLY2(m2, p2, aR2, aI2);
            APPLY2(m3, p3, aR3, aI3);
        }
        for (; e < end; ++e) {
            const int2 m = meta2[e];
            const u32 p = x1p[(size_t)m.x * F + lane];
            APPLY2(m, p, aR0, aI0);
        }

        const size_t b = (size_t)nu * F + lane;
        const u32 iw = initp[b];   // aliases out_real[b]; read-before-write, same thread
        const float oR = unpack_lo(iw) + ((aR0 + aR1) + (aR2 + aR3));
        const float oI = unpack_hi(iw) + ((aI0 + aI1) + (aI2 + aI3));
        __builtin_nontemporal_store(oR, &out_real[b]);
        __builtin_nontemporal_store(oI, &out_imag[b]);
    }
}

// ---------------------------------------------------------------------------
// Fallback (ws too small): f32 init + atomic scatter from packed x1.
// ---------------------------------------------------------------------------
__global__ __launch_bounds__(256) void k_init_out(
    const float* __restrict__ x_real, const float* __restrict__ x_imag,
    const float* __restrict__ weight, const float* __restrict__ bias,
    float* __restrict__ out_real, float* __restrict__ out_imag, int n_nodes)
{
    const int lane = threadIdx.x & 63;
    const int waveId = (blockIdx.x * blockDim.x + threadIdx.x) >> 6;
    const int nWaves = (gridDim.x * blockDim.x) >> 6;
    const float* __restrict__ W0 = weight;
    float w0c[F];
#pragma unroll
    for (int k = 0; k < F; ++k) w0c[k] = W0[k * F + lane];
    const float bf = bias[lane];
    for (int n = waveId; n < n_nodes; n += nWaves) {
        const int nu = __builtin_amdgcn_readfirstlane(n);
        const float4* __restrict__ xr4 = (const float4*)(x_real + (size_t)nu * F);
        const float4* __restrict__ xi4 = (const float4*)(x_imag + (size_t)nu * F);
        float gR = 0.f, gI = 0.f;
#pragma unroll
        for (int k4 = 0; k4 < F / 4; ++k4) {
            const float4 vr = xr4[k4];
            const float4 vi = xi4[k4];
            const float xr[4] = {vr.x, vr.y, vr.z, vr.w};
            const float xi[4] = {vi.x, vi.y, vi.z, vi.w};
#pragma unroll
            for (int j = 0; j < 4; ++j) {
                const int k = 4 * k4 + j;
                gR = fmaf(xr[j], w0c[k], gR);
                gI = fmaf(xi[j], w0c[k], gI);
            }
        }
        const size_t b = (size_t)nu * F + lane;
        out_real[b] = gR + bf;
        out_imag[b] = gI + bf;
    }
}

__global__ __launch_bounds__(256) void k_x1_only(
    const float* __restrict__ x_real, const float* __restrict__ x_imag,
    const float* __restrict__ weight, u32* __restrict__ x1p, int n_nodes)
{
    const int lane = threadIdx.x & 63;
    const int waveId = (blockIdx.x * blockDim.x + threadIdx.x) >> 6;
    const int nWaves = (gridDim.x * blockDim.x) >> 6;
    const float* __restrict__ W1 = weight + F * F;
    float w1c[F];
#pragma unroll
    for (int k = 0; k < F; ++k) w1c[k] = W1[k * F + lane];
    for (int n = waveId; n < n_nodes; n += nWaves) {
        const int nu = __builtin_amdgcn_readfirstlane(n);
        const float4* __restrict__ xr4 = (const float4*)(x_real + (size_t)nu * F);
        const float4* __restrict__ xi4 = (const float4*)(x_imag + (size_t)nu * F);
        float aR = 0.f, aI = 0.f;
#pragma unroll
        for (int k4 = 0; k4 < F / 4; ++k4) {
            const float4 vr = xr4[k4];
            const float4 vi = xi4[k4];
            const float xr[4] = {vr.x, vr.y, vr.z, vr.w};
            const float xi[4] = {vi.x, vi.y, vi.z, vi.w};
#pragma unroll
            for (int j = 0; j < 4; ++j) {
                const int k = 4 * k4 + j;
                aR = fmaf(xr[j], w1c[k], aR);
                aI = fmaf(xi[j], w1c[k], aI);
            }
        }
        x1p[(size_t)nu * F + lane] = pack_bf16x2(aR, aI);
    }
}

__global__ __launch_bounds__(256) void k_scatter(
    const u32* __restrict__ x1p, const int* __restrict__ edge_index,
    const float* __restrict__ norm_real, const float* __restrict__ norm_imag,
    float* __restrict__ out_real, float* __restrict__ out_imag, int n_edges)
{
    const long long gid = (long long)blockIdx.x * blockDim.x + threadIdx.x;
    const long long total = (long long)n_edges * 16;
    if (gid >= total) return;
    const int e = (int)(gid >> 4);
    const int c = (int)(gid & 15);
    const int s = edge_index[e];
    const int d = edge_index[n_edges + e];
    const float cr = norm_real[e];
    const float ci = norm_imag[e];
    const uint4 p4 = *(const uint4*)(x1p + (size_t)d * F + c * 4);
    const u32 pp[4] = {p4.x, p4.y, p4.z, p4.w};
    float* __restrict__ pr = out_real + (size_t)s * F + c * 4;
    float* __restrict__ pi = out_imag + (size_t)s * F + c * 4;
#pragma unroll
    for (int j = 0; j < 4; ++j) {
        const float xr = unpack_lo(pp[j]);
        const float xi = unpack_hi(pp[j]);
        unsafeAtomicAdd(pr + j, fmaf(cr, xr, -ci * xi));
        unsafeAtomicAdd(pi + j, fmaf(cr, xi, ci * xr));
    }
}

extern "C" void kernel_launch(void* const* d_in, const int* in_sizes, int n_in,
                              void* d_out, int out_size, void* d_ws, size_t ws_size,
                              hipStream_t stream) {
    const float* x_real     = (const float*)d_in[0];
    const float* x_imag     = (const float*)d_in[1];
    const float* weight     = (const float*)d_in[2];
    const float* bias       = (const float*)d_in[3];
    const float* norm_real  = (const float*)d_in[4];
    const float* norm_imag  = (const float*)d_in[5];
    const int*   edge_index = (const int*)d_in[6];

    const int n_nodes = in_sizes[0] / F;
    const int n_edges = in_sizes[4];

    float* out_real = (float*)d_out;
    float* out_imag = out_real + (size_t)n_nodes * F;
    u32*   initp    = (u32*)d_out;   // packed bf16 init, overwritten by gather

    // ws layout: [x1p][meta2][offsets][cursor][partials]
    char* ws = (char*)d_ws;
    const size_t x1_bytes   = (size_t)n_nodes * F * sizeof(u32);   // 25.6 MB
    const size_t meta_bytes = (size_t)n_edges * sizeof(int2);      // 12.8 MB
    const size_t off_bytes  = (size_t)(n_nodes + 1) * sizeof(int);
    const size_t cur_bytes  = (size_t)n_nodes * sizeof(int);
    const size_t par_bytes  = 64 * sizeof(int);
    const size_t need = x1_bytes + meta_bytes + off_bytes + cur_bytes + par_bytes;

    u32*  x1p      = (u32*)ws;
    int2* meta2    = (int2*)(ws + x1_bytes);
    int*  offsets  = (int*)(ws + x1_bytes + meta_bytes);
    int*  cursor   = (int*)(ws + x1_bytes + meta_bytes + off_bytes);
    int*  partials = (int*)(ws + x1_bytes + meta_bytes + off_bytes + cur_bytes);

    const int eblocks = (n_edges + 255) / 256;

    if (ws_size >= need) {
        hipMemsetAsync(cursor, 0, cur_bytes, stream);
        const int gblocks = (n_nodes + 63) / 64;
        k_gemm<<<gblocks, 256, 0, stream>>>(
            x_real, x_imag, weight, bias, x1p, initp, n_nodes);
        k_hist<<<eblocks, 256, 0, stream>>>(edge_index, cursor, n_edges);
        const int sblocks = (n_nodes + SCAN_BLOCK * SCAN_ITEMS - 1) / (SCAN_BLOCK * SCAN_ITEMS);
        k_scan1<<<sblocks, SCAN_BLOCK, 0, stream>>>(cursor, offsets, partials, n_nodes);
        k_scan2<<<sblocks, SCAN_BLOCK, 0, stream>>>(offsets, partials, cursor, n_nodes, n_edges);
        k_place<<<eblocks, 256, 0, stream>>>(edge_index, norm_real, norm_imag,
                                             cursor, meta2, n_edges);
        k_gather<<<4096, 256, 0, stream>>>(
            x1p, initp, offsets, meta2, out_real, out_imag, n_nodes);
    } else {
        k_init_out<<<2048, 256, 0, stream>>>(
            x_real, x_imag, weight, bias, out_real, out_imag, n_nodes);
        k_x1_only<<<2048, 256, 0, stream>>>(x_real, x_imag, weight, x1p, n_nodes);
        const long long work = (long long)n_edges * 16;
        const int blocks = (int)((work + 255) / 256);
        k_scatter<<<blocks, 256, 0, stream>>>(
            x1p, edge_index, norm_real, norm_imag, out_real, out_imag, n_edges);
    }
}

// Round 8
// 275.473 us; speedup vs baseline: 1.4544x; 1.1170x over previous
//
#include <hip/hip_runtime.h>

#define F 64
typedef unsigned int u32;
typedef float f8 __attribute__((ext_vector_type(8)));

#define SCAN_BLOCK 1024
#define SCAN_ITEMS 4   // elements per thread -> 4096 per block
#define NPART 8        // node partitions ~ XCDs

// ---- bf16x2 pack/unpack (RNE) ----------------------------------------------
__device__ __forceinline__ u32 pack_bf16x2(float lo, float hi) {
    u32 a = __float_as_uint(lo);
    u32 b = __float_as_uint(hi);
    a = (a + 0x7fffu + ((a >> 16) & 1u)) >> 16;
    b = (b + 0x7fffu + ((b >> 16) & 1u)) >> 16;
    return a | (b << 16);
}
__device__ __forceinline__ float unpack_lo(u32 p) { return __uint_as_float(p << 16); }
__device__ __forceinline__ float unpack_hi(u32 p) { return __uint_as_float(p & 0xffff0000u); }

// ---------------------------------------------------------------------------
// k_gemm: LDS-tiled, n-parallel. One block = 64-node tile. (unchanged)
// ---------------------------------------------------------------------------
__global__ __launch_bounds__(256, 4) void k_gemm(
    const float* __restrict__ x_real, const float* __restrict__ x_imag,
    const float* __restrict__ weight, const float* __restrict__ bias,
    u32* __restrict__ x1p, u32* __restrict__ initp, int n_nodes)
{
    __shared__ float xs[2][64 * 65];

    const int t = threadIdx.x;
    const int base_node = blockIdx.x * 64;

#pragma unroll
    for (int c = 0; c < 8; ++c) {
        const int fq  = t + 256 * c;
        const int arr = fq >> 10;
        const int rem = fq & 1023;
        const int n   = rem >> 4;
        const int c4  = rem & 15;
        const int g   = base_node + n;
        const float* __restrict__ s = arr ? x_imag : x_real;
        float4 v = make_float4(0.f, 0.f, 0.f, 0.f);
        if (g < n_nodes) v = *(const float4*)(s + (size_t)g * F + c4 * 4);
        float* d = &xs[arr][n * 65 + c4 * 4];
        d[0] = v.x; d[1] = v.y; d[2] = v.z; d[3] = v.w;
    }
    __syncthreads();

    const int lane = t & 63;
    const int f0 = __builtin_amdgcn_readfirstlane((t >> 6) * 16);
    const int g = base_node + lane;

    const float* __restrict__ W0 = weight;
    const float* __restrict__ W1 = weight + F * F;

    float aR0[16], aI0[16], aR1[16], aI1[16];
#pragma unroll
    for (int j = 0; j < 16; ++j) { aR0[j] = 0.f; aI0[j] = 0.f; aR1[j] = 0.f; aI1[j] = 0.f; }

    const float* __restrict__ xrow_r = &xs[0][lane * 65];
    const float* __restrict__ xrow_i = &xs[1][lane * 65];

    for (int k0 = 0; k0 < F; k0 += 4) {
#pragma unroll
        for (int kk = 0; kk < 4; ++kk) {
            const int k = k0 + kk;
            const float xr = xrow_r[k];
            const float xi = xrow_i[k];
            const f8 wa0 = *(const f8*)(W0 + k * F + f0);
            const f8 wb0 = *(const f8*)(W0 + k * F + f0 + 8);
            const f8 wa1 = *(const f8*)(W1 + k * F + f0);
            const f8 wb1 = *(const f8*)(W1 + k * F + f0 + 8);
#pragma unroll
            for (int j = 0; j < 8; ++j) {
                aR0[j]     = fmaf(xr, wa0[j], aR0[j]);
                aI0[j]     = fmaf(xi, wa0[j], aI0[j]);
                aR1[j]     = fmaf(xr, wa1[j], aR1[j]);
                aI1[j]     = fmaf(xi, wa1[j], aI1[j]);
                aR0[8 + j] = fmaf(xr, wb0[j], aR0[8 + j]);
                aI0[8 + j] = fmaf(xi, wb0[j], aI0[8 + j]);
                aR1[8 + j] = fmaf(xr, wb1[j], aR1[8 + j]);
                aI1[8 + j] = fmaf(xi, wb1[j], aI1[8 + j]);
            }
        }
    }

    if (g < n_nodes) {
        const f8 b0 = *(const f8*)(bias + f0);
        const f8 b1 = *(const f8*)(bias + f0 + 8);
        u32 pi[16], pw[16];
#pragma unroll
        for (int j = 0; j < 8; ++j) {
            pi[j]     = pack_bf16x2(aR0[j] + b0[j],     aI0[j] + b0[j]);
            pi[8 + j] = pack_bf16x2(aR0[8 + j] + b1[j], aI0[8 + j] + b1[j]);
            pw[j]     = pack_bf16x2(aR1[j],     aI1[j]);
            pw[8 + j] = pack_bf16x2(aR1[8 + j], aI1[8 + j]);
        }
        uint4* __restrict__ di = (uint4*)(initp + (size_t)g * F + f0);
        uint4* __restrict__ dw = (uint4*)(x1p  + (size_t)g * F + f0);
#pragma unroll
        for (int q = 0; q < 4; ++q) {
            di[q] = make_uint4(pi[4 * q], pi[4 * q + 1], pi[4 * q + 2], pi[4 * q + 3]);
            dw[q] = make_uint4(pw[4 * q], pw[4 * q + 1], pw[4 * q + 2], pw[4 * q + 3]);
        }
    }
}

// ---------------------------------------------------------------------------
// CSR build
// ---------------------------------------------------------------------------
__global__ void k_hist(const int* __restrict__ src, int* __restrict__ counts, int n_edges) {
    int e = blockIdx.x * 256 + threadIdx.x;
    if (e < n_edges) atomicAdd(&counts[src[e]], 1);
}

__global__ __launch_bounds__(1024) void k_scan1(
    const int* __restrict__ cnt, int* __restrict__ pre,
    int* __restrict__ partials, int n)
{
    __shared__ int wsum[16];
    const int t = threadIdx.x;
    const int lane = t & 63, wid = t >> 6;
    const int base = blockIdx.x * (SCAN_BLOCK * SCAN_ITEMS) + t * SCAN_ITEMS;

    int v[SCAN_ITEMS];
    int local = 0;
#pragma unroll
    for (int j = 0; j < SCAN_ITEMS; ++j) {
        const int idx = base + j;
        const int c = (idx < n) ? cnt[idx] : 0;
        v[j] = local;
        local += c;
    }
    int incl = local;
#pragma unroll
    for (int d = 1; d < 64; d <<= 1) {
        int x = __shfl_up(incl, d);
        if (lane >= d) incl += x;
    }
    if (lane == 63) wsum[wid] = incl;
    __syncthreads();
    if (wid == 0) {
        int s = (lane < 16) ? wsum[lane] : 0;
#pragma unroll
        for (int d = 1; d < 16; d <<= 1) {
            int x = __shfl_up(s, d);
            if (lane >= d) s += x;
        }
        if (lane < 16) wsum[lane] = s;
    }
    __syncthreads();
    const int texcl = (incl - local) + (wid ? wsum[wid - 1] : 0);
#pragma unroll
    for (int j = 0; j < SCAN_ITEMS; ++j) {
        const int idx = base + j;
        if (idx < n) pre[idx] = texcl + v[j];
    }
    if (t == SCAN_BLOCK - 1) partials[blockIdx.x] = texcl + local;
}

__global__ __launch_bounds__(1024) void k_scan2(
    int* __restrict__ pre, const int* __restrict__ partials,
    int* __restrict__ cursor, int n, int n_edges)
{
    __shared__ int s_off;
    const int t = threadIdx.x;
    if (t < 64) {
        int val = (t < blockIdx.x) ? partials[t] : 0;
#pragma unroll
        for (int d = 32; d > 0; d >>= 1) val += __shfl_down(val, d);
        if (t == 0) s_off = val;
    }
    __syncthreads();
    const int boff = s_off;
    const int base = blockIdx.x * (SCAN_BLOCK * SCAN_ITEMS) + t * SCAN_ITEMS;
#pragma unroll
    for (int j = 0; j < SCAN_ITEMS; ++j) {
        const int idx = base + j;
        if (idx < n) {
            const int o = boff + pre[idx];
            pre[idx] = o;
            cursor[idx] = o;
        }
    }
    if (blockIdx.x == 0 && t == 0) pre[n] = n_edges;
}

// ---------------------------------------------------------------------------
// k_place: XCD-partitioned. part = bid&7 handles src in [lo,hi) only; its
// meta sub-region (1.6 MB) is written by one XCD's L2 -> no line ping-pong.
// Every partition scans full src (L3-served); dst/norm loads predicated.
// ---------------------------------------------------------------------------
__global__ __launch_bounds__(256) void k_place(
    const int* __restrict__ edge_index,
    const float* __restrict__ nr, const float* __restrict__ ni,
    int* __restrict__ cursor, int2* __restrict__ meta2,
    int n_edges, int n_nodes)
{
    const int part = blockIdx.x & (NPART - 1);
    const int grp  = blockIdx.x >> 3;
    const int ngrp = gridDim.x >> 3;
    const int lo = (int)((long long)part * n_nodes / NPART);
    const int hi = (int)((long long)(part + 1) * n_nodes / NPART);

    for (int e = grp * 256 + threadIdx.x; e < n_edges; e += ngrp * 256) {
        const int s = edge_index[e];
        if (s >= lo && s < hi) {
            const int pos = atomicAdd(&cursor[s], 1);
            int2 m;
            m.x = edge_index[n_edges + e];
            m.y = (int)pack_bf16x2(nr[e], ni[e]);
            meta2[pos] = m;
        }
    }
}

// ---------------------------------------------------------------------------
// Gather: partitioned to match k_place (part = bid&7 -> same node range),
// contiguous node chunk per wave so meta reads are sequential & XCD-local.
// ---------------------------------------------------------------------------
#define APPLY2(m, p, aR, aI)                                  \
    do {                                                      \
        const float cr = unpack_lo((u32)(m).y);               \
        const float ci = unpack_hi((u32)(m).y);               \
        const float xr = unpack_lo(p);                        \
        const float xi = unpack_hi(p);                        \
        aR = fmaf(cr, xr, fmaf(-ci, xi, aR));                 \
        aI = fmaf(cr, xi, fmaf(ci, xr, aI));                  \
    } while (0)

__global__ __launch_bounds__(256) void k_gather(
    const u32* __restrict__ x1p, const u32* __restrict__ initp,
    const int* __restrict__ offsets, const int2* __restrict__ meta2,
    float* __restrict__ out_real, float* __restrict__ out_imag,
    int n_nodes)
{
    const int part = blockIdx.x & (NPART - 1);
    const int lane = threadIdx.x & 63;
    const int wip = ((blockIdx.x >> 3) << 2) + (threadIdx.x >> 6);  // wave in part
    const int wpp = (gridDim.x >> 3) << 2;                          // waves per part

    const int lo = (int)((long long)part * n_nodes / NPART);
    const int hi = (int)((long long)(part + 1) * n_nodes / NPART);
    const int chunk = (hi - lo + wpp - 1) / wpp;
    const int nbeg = lo + wip * chunk;
    const int nend = min(nbeg + chunk, hi);

    for (int n = nbeg; n < nend; ++n) {
        const int nu = __builtin_amdgcn_readfirstlane(n);
        const int beg = __builtin_amdgcn_readfirstlane(offsets[nu]);
        const int end = __builtin_amdgcn_readfirstlane(offsets[nu + 1]);

        float aR0 = 0.f, aI0 = 0.f, aR1 = 0.f, aI1 = 0.f;
        float aR2 = 0.f, aI2 = 0.f, aR3 = 0.f, aI3 = 0.f;

        int e = beg;
        for (; e + 8 <= end; e += 8) {
            const int2 m0 = meta2[e + 0];
            const int2 m1 = meta2[e + 1];
            const int2 m2 = meta2[e + 2];
            const int2 m3 = meta2[e + 3];
            const int2 m4 = meta2[e + 4];
            const int2 m5 = meta2[e + 5];
            const int2 m6 = meta2[e + 6];
            const int2 m7 = meta2[e + 7];
            const u32 p0 = x1p[(size_t)m0.x * F + lane];
            const u32 p1 = x1p[(size_t)m1.x * F + lane];
            const u32 p2 = x1p[(size_t)m2.x * F + lane];
            const u32 p3 = x1p[(size_t)m3.x * F + lane];
            const u32 p4 = x1p[(size_t)m4.x * F + lane];
            const u32 p5 = x1p[(size_t)m5.x * F + lane];
            const u32 p6 = x1p[(size_t)m6.x * F + lane];
            const u32 p7 = x1p[(size_t)m7.x * F + lane];
            APPLY2(m0, p0, aR0, aI0);
            APPLY2(m1, p1, aR1, aI1);
            APPLY2(m2, p2, aR2, aI2);
            APPLY2(m3, p3, aR3, aI3);
            APPLY2(m4, p4, aR0, aI0);
            APPLY2(m5, p5, aR1, aI1);
            APPLY2(m6, p6, aR2, aI2);
            APPLY2(m7, p7, aR3, aI3);
        }
        for (; e + 4 <= end; e += 4) {
            const int2 m0 = meta2[e + 0];
            const int2 m1 = meta2[e + 1];
            const int2 m2 = meta2[e + 2];
            const int2 m3 = meta2[e + 3];
            const u32 p0 = x1p[(size_t)m0.x * F + lane];
            const u32 p1 = x1p[(size_t)m1.x * F + lane];
            const u32 p2 = x1p[(size_t)m2.x * F + lane];
            const u32 p3 = x1p[(size_t)m3.x * F + lane];
            APPLY2(m0, p0, aR0, aI0);
            APPLY2(m1, p1, aR1, aI1);
            APPLY2(m2, p2, aR2, aI2);
            APPLY2(m3, p3, aR3, aI3);
        }
        for (; e < end; ++e) {
            const int2 m = meta2[e];
            const u32 p = x1p[(size_t)m.x * F + lane];
            APPLY2(m, p, aR0, aI0);
        }

        const size_t b = (size_t)nu * F + lane;
        const u32 iw = initp[b];   // aliases out_real[b]; read-before-write, same thread
        const float oR = unpack_lo(iw) + ((aR0 + aR1) + (aR2 + aR3));
        const float oI = unpack_hi(iw) + ((aI0 + aI1) + (aI2 + aI3));
        __builtin_nontemporal_store(oR, &out_real[b]);
        __builtin_nontemporal_store(oI, &out_imag[b]);
    }
}

// ---------------------------------------------------------------------------
// Fallback (ws too small): f32 init + atomic scatter from packed x1.
// ---------------------------------------------------------------------------
__global__ __launch_bounds__(256) void k_init_out(
    const float* __restrict__ x_real, const float* __restrict__ x_imag,
    const float* __restrict__ weight, const float* __restrict__ bias,
    float* __restrict__ out_real, float* __restrict__ out_imag, int n_nodes)
{
    const int lane = threadIdx.x & 63;
    const int waveId = (blockIdx.x * blockDim.x + threadIdx.x) >> 6;
    const int nWaves = (gridDim.x * blockDim.x) >> 6;
    const float* __restrict__ W0 = weight;
    float w0c[F];
#pragma unroll
    for (int k = 0; k < F; ++k) w0c[k] = W0[k * F + lane];
    const float bf = bias[lane];
    for (int n = waveId; n < n_nodes; n += nWaves) {
        const int nu = __builtin_amdgcn_readfirstlane(n);
        const float4* __restrict__ xr4 = (const float4*)(x_real + (size_t)nu * F);
        const float4* __restrict__ xi4 = (const float4*)(x_imag + (size_t)nu * F);
        float gR = 0.f, gI = 0.f;
#pragma unroll
        for (int k4 = 0; k4 < F / 4; ++k4) {
            const float4 vr = xr4[k4];
            const float4 vi = xi4[k4];
            const float xr[4] = {vr.x, vr.y, vr.z, vr.w};
            const float xi[4] = {vi.x, vi.y, vi.z, vi.w};
#pragma unroll
            for (int j = 0; j < 4; ++j) {
                const int k = 4 * k4 + j;
                gR = fmaf(xr[j], w0c[k], gR);
                gI = fmaf(xi[j], w0c[k], gI);
            }
        }
        const size_t b = (size_t)nu * F + lane;
        out_real[b] = gR + bf;
        out_imag[b] = gI + bf;
    }
}

__global__ __launch_bounds__(256) void k_x1_only(
    const float* __restrict__ x_real, const float* __restrict__ x_imag,
    const float* __restrict__ weight, u32* __restrict__ x1p, int n_nodes)
{
    const int lane = threadIdx.x & 63;
    const int waveId = (blockIdx.x * blockDim.x + threadIdx.x) >> 6;
    const int nWaves = (gridDim.x * blockDim.x) >> 6;
    const float* __restrict__ W1 = weight + F * F;
    float w1c[F];
#pragma unroll
    for (int k = 0; k < F; ++k) w1c[k] = W1[k * F + lane];
    for (int n = waveId; n < n_nodes; n += nWaves) {
        const int nu = __builtin_amdgcn_readfirstlane(n);
        const float4* __restrict__ xr4 = (const float4*)(x_real + (size_t)nu * F);
        const float4* __restrict__ xi4 = (const float4*)(x_imag + (size_t)nu * F);
        float aR = 0.f, aI = 0.f;
#pragma unroll
        for (int k4 = 0; k4 < F / 4; ++k4) {
            const float4 vr = xr4[k4];
            const float4 vi = xi4[k4];
            const float xr[4] = {vr.x, vr.y, vr.z, vr.w};
            const float xi[4] = {vi.x, vi.y, vi.z, vi.w};
#pragma unroll
            for (int j = 0; j < 4; ++j) {
                const int k = 4 * k4 + j;
                aR = fmaf(xr[j], w1c[k], aR);
                aI = fmaf(xi[j], w1c[k], aI);
            }
        }
        x1p[(size_t)nu * F + lane] = pack_bf16x2(aR, aI);
    }
}

__global__ __launch_bounds__(256) void k_scatter(
    const u32* __restrict__ x1p, const int* __restrict__ edge_index,
    const float* __restrict__ norm_real, const float* __restrict__ norm_imag,
    float* __restrict__ out_real, float* __restrict__ out_imag, int n_edges)
{
    const long long gid = (long long)blockIdx.x * blockDim.x + threadIdx.x;
    const long long total = (long long)n_edges * 16;
    if (gid >= total) return;
    const int e = (int)(gid >> 4);
    const int c = (int)(gid & 15);
    const int s = edge_index[e];
    const int d = edge_index[n_edges + e];
    const float cr = norm_real[e];
    const float ci = norm_imag[e];
    const uint4 p4 = *(const uint4*)(x1p + (size_t)d * F + c * 4);
    const u32 pp[4] = {p4.x, p4.y, p4.z, p4.w};
    float* __restrict__ pr = out_real + (size_t)s * F + c * 4;
    float* __restrict__ pi = out_imag + (size_t)s * F + c * 4;
#pragma unroll
    for (int j = 0; j < 4; ++j) {
        const float xr = unpack_lo(pp[j]);
        const float xi = unpack_hi(pp[j]);
        unsafeAtomicAdd(pr + j, fmaf(cr, xr, -ci * xi));
        unsafeAtomicAdd(pi + j, fmaf(cr, xi, ci * xr));
    }
}

extern "C" void kernel_launch(void* const* d_in, const int* in_sizes, int n_in,
                              void* d_out, int out_size, void* d_ws, size_t ws_size,
                              hipStream_t stream) {
    const float* x_real     = (const float*)d_in[0];
    const float* x_imag     = (const float*)d_in[1];
    const float* weight     = (const float*)d_in[2];
    const float* bias       = (const float*)d_in[3];
    const float* norm_real  = (const float*)d_in[4];
    const float* norm_imag  = (const float*)d_in[5];
    const int*   edge_index = (const int*)d_in[6];

    const int n_nodes = in_sizes[0] / F;
    const int n_edges = in_sizes[4];

    float* out_real = (float*)d_out;
    float* out_imag = out_real + (size_t)n_nodes * F;
    u32*   initp    = (u32*)d_out;   // packed bf16 init, overwritten by gather

    // ws layout: [x1p][meta2][offsets][cursor][partials]
    char* ws = (char*)d_ws;
    const size_t x1_bytes   = (size_t)n_nodes * F * sizeof(u32);   // 25.6 MB
    const size_t meta_bytes = (size_t)n_edges * sizeof(int2);      // 12.8 MB
    const size_t off_bytes  = (size_t)(n_nodes + 1) * sizeof(int);
    const size_t cur_bytes  = (size_t)n_nodes * sizeof(int);
    const size_t par_bytes  = 64 * sizeof(int);
    const size_t need = x1_bytes + meta_bytes + off_bytes + cur_bytes + par_bytes;

    u32*  x1p      = (u32*)ws;
    int2* meta2    = (int2*)(ws + x1_bytes);
    int*  offsets  = (int*)(ws + x1_bytes + meta_bytes);
    int*  cursor   = (int*)(ws + x1_bytes + meta_bytes + off_bytes);
    int*  partials = (int*)(ws + x1_bytes + meta_bytes + off_bytes + cur_bytes);

    const int eblocks = (n_edges + 255) / 256;

    if (ws_size >= need) {
        hipMemsetAsync(cursor, 0, cur_bytes, stream);
        const int gblocks = (n_nodes + 63) / 64;
        k_gemm<<<gblocks, 256, 0, stream>>>(
            x_real, x_imag, weight, bias, x1p, initp, n_nodes);
        k_hist<<<eblocks, 256, 0, stream>>>(edge_index, cursor, n_edges);
        const int sblocks = (n_nodes + SCAN_BLOCK * SCAN_ITEMS - 1) / (SCAN_BLOCK * SCAN_ITEMS);
        k_scan1<<<sblocks, SCAN_BLOCK, 0, stream>>>(cursor, offsets, partials, n_nodes);
        k_scan2<<<sblocks, SCAN_BLOCK, 0, stream>>>(offsets, partials, cursor, n_nodes, n_edges);
        k_place<<<2048, 256, 0, stream>>>(edge_index, norm_real, norm_imag,
                                          cursor, meta2, n_edges, n_nodes);
        k_gather<<<2048, 256, 0, stream>>>(
            x1p, initp, offsets, meta2, out_real, out_imag, n_nodes);
    } else {
        k_init_out<<<2048, 256, 0, stream>>>(
            x_real, x_imag, weight, bias, out_real, out_imag, n_nodes);
        k_x1_only<<<2048, 256, 0, stream>>>(x_real, x_imag, weight, x1p, n_nodes);
        const long long work = (long long)n_edges * 16;
        const int blocks = (int)((work + 255) / 256);
        k_scatter<<<blocks, 256, 0, stream>>>(
            x1p, edge_index, norm_real, norm_imag, out_real, out_imag, n_edges);
    }
}

// Round 10
// 253.847 us; speedup vs baseline: 1.5783x; 1.0852x over previous
//
#include <hip/hip_runtime.h>

#define F 64
typedef unsigned int u32;
typedef unsigned long long u64;
typedef float f8 __attribute__((ext_vector_type(8)));

#define SCAN_BLOCK 1024
#define SCAN_ITEMS 4   // elements per thread -> 4096 per block
#define NPART 8        // node partitions ~ XCDs

// ---- bf16x2 pack/unpack (RNE) ----------------------------------------------
__device__ __forceinline__ u32 pack_bf16x2(float lo, float hi) {
    u32 a = __float_as_uint(lo);
    u32 b = __float_as_uint(hi);
    a = (a + 0x7fffu + ((a >> 16) & 1u)) >> 16;
    b = (b + 0x7fffu + ((b >> 16) & 1u)) >> 16;
    return a | (b << 16);
}
__device__ __forceinline__ float unpack_lo(u32 p) { return __uint_as_float(p << 16); }
__device__ __forceinline__ float unpack_hi(u32 p) { return __uint_as_float(p & 0xffff0000u); }

// ---------------------------------------------------------------------------
// k_gemm: LDS-tiled GEMMs + fused edge histogram.
//   initp[n][f] = pack_bf16(x_r@W0+b, x_i@W0+b)   -> d_out region
//   x1p[n][f]   = pack_bf16(x_r@W1,   x_i@W1)     -> ws
//   counts[src[e]]++ (nt loads, atomics hidden under FMA phase)
// ---------------------------------------------------------------------------
__global__ __launch_bounds__(256, 4) void k_gemm(
    const float* __restrict__ x_real, const float* __restrict__ x_imag,
    const float* __restrict__ weight, const float* __restrict__ bias,
    u32* __restrict__ x1p, u32* __restrict__ initp,
    const int* __restrict__ edge_src, int* __restrict__ counts,
    int n_nodes, int n_edges)
{
    __shared__ float xs[2][64 * 65];

    const int t = threadIdx.x;
    const int base_node = blockIdx.x * 64;

#pragma unroll
    for (int c = 0; c < 8; ++c) {
        const int fq  = t + 256 * c;
        const int arr = fq >> 10;
        const int rem = fq & 1023;
        const int n   = rem >> 4;
        const int c4  = rem & 15;
        const int g   = base_node + n;
        const float* __restrict__ s = arr ? x_imag : x_real;
        float4 v = make_float4(0.f, 0.f, 0.f, 0.f);
        if (g < n_nodes) v = *(const float4*)(s + (size_t)g * F + c4 * 4);
        float* d = &xs[arr][n * 65 + c4 * 4];
        d[0] = v.x; d[1] = v.y; d[2] = v.z; d[3] = v.w;
    }

    // fused histogram: fire-and-forget atomics, hidden under the FMA phase
    {
        const int tid = blockIdx.x * 256 + t;
        const int stride = gridDim.x * 256;
        for (int e = tid; e < n_edges; e += stride) {
            const int s = __builtin_nontemporal_load(edge_src + e);
            atomicAdd(&counts[s], 1);
        }
    }
    __syncthreads();

    const int lane = t & 63;
    const int f0 = __builtin_amdgcn_readfirstlane((t >> 6) * 16);
    const int g = base_node + lane;

    const float* __restrict__ W0 = weight;
    const float* __restrict__ W1 = weight + F * F;

    float aR0[16], aI0[16], aR1[16], aI1[16];
#pragma unroll
    for (int j = 0; j < 16; ++j) { aR0[j] = 0.f; aI0[j] = 0.f; aR1[j] = 0.f; aI1[j] = 0.f; }

    const float* __restrict__ xrow_r = &xs[0][lane * 65];
    const float* __restrict__ xrow_i = &xs[1][lane * 65];

    for (int k0 = 0; k0 < F; k0 += 4) {
#pragma unroll
        for (int kk = 0; kk < 4; ++kk) {
            const int k = k0 + kk;
            const float xr = xrow_r[k];
            const float xi = xrow_i[k];
            const f8 wa0 = *(const f8*)(W0 + k * F + f0);
            const f8 wb0 = *(const f8*)(W0 + k * F + f0 + 8);
            const f8 wa1 = *(const f8*)(W1 + k * F + f0);
            const f8 wb1 = *(const f8*)(W1 + k * F + f0 + 8);
#pragma unroll
            for (int j = 0; j < 8; ++j) {
                aR0[j]     = fmaf(xr, wa0[j], aR0[j]);
                aI0[j]     = fmaf(xi, wa0[j], aI0[j]);
                aR1[j]     = fmaf(xr, wa1[j], aR1[j]);
                aI1[j]     = fmaf(xi, wa1[j], aI1[j]);
                aR0[8 + j] = fmaf(xr, wb0[j], aR0[8 + j]);
                aI0[8 + j] = fmaf(xi, wb0[j], aI0[8 + j]);
                aR1[8 + j] = fmaf(xr, wb1[j], aR1[8 + j]);
                aI1[8 + j] = fmaf(xi, wb1[j], aI1[8 + j]);
            }
        }
    }

    if (g < n_nodes) {
        const f8 b0 = *(const f8*)(bias + f0);
        const f8 b1 = *(const f8*)(bias + f0 + 8);
        u32 pi[16], pw[16];
#pragma unroll
        for (int j = 0; j < 8; ++j) {
            pi[j]     = pack_bf16x2(aR0[j] + b0[j],     aI0[j] + b0[j]);
            pi[8 + j] = pack_bf16x2(aR0[8 + j] + b1[j], aI0[8 + j] + b1[j]);
            pw[j]     = pack_bf16x2(aR1[j],     aI1[j]);
            pw[8 + j] = pack_bf16x2(aR1[8 + j], aI1[8 + j]);
        }
        uint4* __restrict__ di = (uint4*)(initp + (size_t)g * F + f0);
        uint4* __restrict__ dw = (uint4*)(x1p  + (size_t)g * F + f0);
#pragma unroll
        for (int q = 0; q < 4; ++q) {
            di[q] = make_uint4(pi[4 * q], pi[4 * q + 1], pi[4 * q + 2], pi[4 * q + 3]);
            dw[q] = make_uint4(pw[4 * q], pw[4 * q + 1], pw[4 * q + 2], pw[4 * q + 3]);
        }
    }
}

// ---------------------------------------------------------------------------
// Scan (two-level, unchanged)
// ---------------------------------------------------------------------------
__global__ __launch_bounds__(1024) void k_scan1(
    const int* __restrict__ cnt, int* __restrict__ pre,
    int* __restrict__ partials, int n)
{
    __shared__ int wsum[16];
    const int t = threadIdx.x;
    const int lane = t & 63, wid = t >> 6;
    const int base = blockIdx.x * (SCAN_BLOCK * SCAN_ITEMS) + t * SCAN_ITEMS;

    int v[SCAN_ITEMS];
    int local = 0;
#pragma unroll
    for (int j = 0; j < SCAN_ITEMS; ++j) {
        const int idx = base + j;
        const int c = (idx < n) ? cnt[idx] : 0;
        v[j] = local;
        local += c;
    }
    int incl = local;
#pragma unroll
    for (int d = 1; d < 64; d <<= 1) {
        int x = __shfl_up(incl, d);
        if (lane >= d) incl += x;
    }
    if (lane == 63) wsum[wid] = incl;
    __syncthreads();
    if (wid == 0) {
        int s = (lane < 16) ? wsum[lane] : 0;
#pragma unroll
        for (int d = 1; d < 16; d <<= 1) {
            int x = __shfl_up(s, d);
            if (lane >= d) s += x;
        }
        if (lane < 16) wsum[lane] = s;
    }
    __syncthreads();
    const int texcl = (incl - local) + (wid ? wsum[wid - 1] : 0);
#pragma unroll
    for (int j = 0; j < SCAN_ITEMS; ++j) {
        const int idx = base + j;
        if (idx < n) pre[idx] = texcl + v[j];
    }
    if (t == SCAN_BLOCK - 1) partials[blockIdx.x] = texcl + local;
}

__global__ __launch_bounds__(1024) void k_scan2(
    int* __restrict__ pre, const int* __restrict__ partials,
    int* __restrict__ cursor, int n, int n_edges)
{
    __shared__ int s_off;
    const int t = threadIdx.x;
    if (t < 64) {
        int val = (t < blockIdx.x) ? partials[t] : 0;
#pragma unroll
        for (int d = 32; d > 0; d >>= 1) val += __shfl_down(val, d);
        if (t == 0) s_off = val;
    }
    __syncthreads();
    const int boff = s_off;
    const int base = blockIdx.x * (SCAN_BLOCK * SCAN_ITEMS) + t * SCAN_ITEMS;
#pragma unroll
    for (int j = 0; j < SCAN_ITEMS; ++j) {
        const int idx = base + j;
        if (idx < n) {
            const int o = boff + pre[idx];
            pre[idx] = o;
            cursor[idx] = o;
        }
    }
    if (blockIdx.x == 0 && t == 0) pre[n] = n_edges;
}

// ---------------------------------------------------------------------------
// k_place: XCD-partitioned + NON-TEMPORAL edge-stream loads so the streams
// don't evict dirty meta lines from L2. meta stored as u64 (dst | norms<<32).
// ---------------------------------------------------------------------------
__global__ __launch_bounds__(256) void k_place(
    const int* __restrict__ edge_index,
    const float* __restrict__ nr, const float* __restrict__ ni,
    int* __restrict__ cursor, u64* __restrict__ meta2,
    int n_edges, int n_nodes)
{
    const int part = blockIdx.x & (NPART - 1);
    const int grp  = blockIdx.x >> 3;
    const int ngrp = gridDim.x >> 3;
    const int lo = (int)((long long)part * n_nodes / NPART);
    const int hi = (int)((long long)(part + 1) * n_nodes / NPART);

    for (int e = grp * 256 + threadIdx.x; e < n_edges; e += ngrp * 256) {
        const int s = __builtin_nontemporal_load(edge_index + e);
        if (s >= lo && s < hi) {
            const int pos = atomicAdd(&cursor[s], 1);
            const u32 d = (u32)__builtin_nontemporal_load(edge_index + n_edges + e);
            const u32 nn = pack_bf16x2(__builtin_nontemporal_load(nr + e),
                                       __builtin_nontemporal_load(ni + e));
            meta2[pos] = (u64)d | ((u64)nn << 32);
        }
    }
}

// ---------------------------------------------------------------------------
// Gather: partitioned (matches k_place); nt loads for one-touch streams
// (meta2, initp) so L2 stays reserved for the reused x1p gather set.
// ---------------------------------------------------------------------------
#define APPLY2(m, p, aR, aI)                                  \
    do {                                                      \
        const u32 nnv = (u32)((m) >> 32);                     \
        const float cr = unpack_lo(nnv);                      \
        const float ci = unpack_hi(nnv);                      \
        const float xr = unpack_lo(p);                        \
        const float xi = unpack_hi(p);                        \
        aR = fmaf(cr, xr, fmaf(-ci, xi, aR));                 \
        aI = fmaf(cr, xi, fmaf(ci, xr, aI));                  \
    } while (0)

__global__ __launch_bounds__(256) void k_gather(
    const u32* __restrict__ x1p, const u32* __restrict__ initp,
    const int* __restrict__ offsets, const u64* __restrict__ meta2,
    float* __restrict__ out_real, float* __restrict__ out_imag,
    int n_nodes)
{
    const int part = blockIdx.x & (NPART - 1);
    const int lane = threadIdx.x & 63;
    const int wip = ((blockIdx.x >> 3) << 2) + (threadIdx.x >> 6);
    const int wpp = (gridDim.x >> 3) << 2;

    const int lo = (int)((long long)part * n_nodes / NPART);
    const int hi = (int)((long long)(part + 1) * n_nodes / NPART);
    const int chunk = (hi - lo + wpp - 1) / wpp;
    const int nbeg = lo + wip * chunk;
    const int nend = min(nbeg + chunk, hi);

    for (int n = nbeg; n < nend; ++n) {
        const int nu = __builtin_amdgcn_readfirstlane(n);
        const int beg = __builtin_amdgcn_readfirstlane(offsets[nu]);
        const int end = __builtin_amdgcn_readfirstlane(offsets[nu + 1]);

        float aR0 = 0.f, aI0 = 0.f, aR1 = 0.f, aI1 = 0.f;
        float aR2 = 0.f, aI2 = 0.f, aR3 = 0.f, aI3 = 0.f;

        int e = beg;
        for (; e + 8 <= end; e += 8) {
            const u64 m0 = __builtin_nontemporal_load(meta2 + e + 0);
            const u64 m1 = __builtin_nontemporal_load(meta2 + e + 1);
            const u64 m2 = __builtin_nontemporal_load(meta2 + e + 2);
            const u64 m3 = __builtin_nontemporal_load(meta2 + e + 3);
            const u64 m4 = __builtin_nontemporal_load(meta2 + e + 4);
            const u64 m5 = __builtin_nontemporal_load(meta2 + e + 5);
            const u64 m6 = __builtin_nontemporal_load(meta2 + e + 6);
            const u64 m7 = __builtin_nontemporal_load(meta2 + e + 7);
            const u32 p0 = x1p[(size_t)(u32)m0 * F + lane];
            const u32 p1 = x1p[(size_t)(u32)m1 * F + lane];
            const u32 p2 = x1p[(size_t)(u32)m2 * F + lane];
            const u32 p3 = x1p[(size_t)(u32)m3 * F + lane];
            const u32 p4 = x1p[(size_t)(u32)m4 * F + lane];
            const u32 p5 = x1p[(size_t)(u32)m5 * F + lane];
            const u32 p6 = x1p[(size_t)(u32)m6 * F + lane];
            const u32 p7 = x1p[(size_t)(u32)m7 * F + lane];
            APPLY2(m0, p0, aR0, aI0);
            APPLY2(m1, p1, aR1, aI1);
            APPLY2(m2, p2, aR2, aI2);
            APPLY2(m3, p3, aR3, aI3);
            APPLY2(m4, p4, aR0, aI0);
            APPLY2(m5, p5, aR1, aI1);
            APPLY2(m6, p6, aR2, aI2);
            APPLY2(m7, p7, aR3, aI3);
        }
        for (; e + 4 <= end; e += 4) {
            const u64 m0 = __builtin_nontemporal_load(meta2 + e + 0);
            const u64 m1 = __builtin_nontemporal_load(meta2 + e + 1);
            const u64 m2 = __builtin_nontemporal_load(meta2 + e + 2);
            const u64 m3 = __builtin_nontemporal_load(meta2 + e + 3);
            const u32 p0 = x1p[(size_t)(u32)m0 * F + lane];
            const u32 p1 = x1p[(size_t)(u32)m1 * F + lane];
            const u32 p2 = x1p[(size_t)(u32)m2 * F + lane];
            const u32 p3 = x1p[(size_t)(u32)m3 * F + lane];
            APPLY2(m0, p0, aR0, aI0);
            APPLY2(m1, p1, aR1, aI1);
            APPLY2(m2, p2, aR2, aI2);
            APPLY2(m3, p3, aR3, aI3);
        }
        for (; e < end; ++e) {
            const u64 m = __builtin_nontemporal_load(meta2 + e);
            const u32 p = x1p[(size_t)(u32)m * F + lane];
            APPLY2(m, p, aR0, aI0);
        }

        const size_t b = (size_t)nu * F + lane;
        const u32 iw = __builtin_nontemporal_load(initp + b); // aliases out_real[b]
        const float oR = unpack_lo(iw) + ((aR0 + aR1) + (aR2 + aR3));
        const float oI = unpack_hi(iw) + ((aI0 + aI1) + (aI2 + aI3));
        __builtin_nontemporal_store(oR, &out_real[b]);
        __builtin_nontemporal_store(oI, &out_imag[b]);
    }
}

// ---------------------------------------------------------------------------
// Fallback (ws too small): f32 init + atomic scatter from packed x1.
// ---------------------------------------------------------------------------
__global__ __launch_bounds__(256) void k_init_out(
    const float* __restrict__ x_real, const float* __restrict__ x_imag,
    const float* __restrict__ weight, const float* __restrict__ bias,
    float* __restrict__ out_real, float* __restrict__ out_imag, int n_nodes)
{
    const int lane = threadIdx.x & 63;
    const int waveId = (blockIdx.x * blockDim.x + threadIdx.x) >> 6;
    const int nWaves = (gridDim.x * blockDim.x) >> 6;
    const float* __restrict__ W0 = weight;
    float w0c[F];
#pragma unroll
    for (int k = 0; k < F; ++k) w0c[k] = W0[k * F + lane];
    const float bf = bias[lane];
    for (int n = waveId; n < n_nodes; n += nWaves) {
        const int nu = __builtin_amdgcn_readfirstlane(n);
        const float4* __restrict__ xr4 = (const float4*)(x_real + (size_t)nu * F);
        const float4* __restrict__ xi4 = (const float4*)(x_imag + (size_t)nu * F);
        float gR = 0.f, gI = 0.f;
#pragma unroll
        for (int k4 = 0; k4 < F / 4; ++k4) {
            const float4 vr = xr4[k4];
            const float4 vi = xi4[k4];
            const float xr[4] = {vr.x, vr.y, vr.z, vr.w};
            const float xi[4] = {vi.x, vi.y, vi.z, vi.w};
#pragma unroll
            for (int j = 0; j < 4; ++j) {
                const int k = 4 * k4 + j;
                gR = fmaf(xr[j], w0c[k], gR);
                gI = fmaf(xi[j], w0c[k], gI);
            }
        }
        const size_t b = (size_t)nu * F + lane;
        out_real[b] = gR + bf;
        out_imag[b] = gI + bf;
    }
}

__global__ __launch_bounds__(256) void k_x1_only(
    const float* __restrict__ x_real, const float* __restrict__ x_imag,
    const float* __restrict__ weight, u32* __restrict__ x1p, int n_nodes)
{
    const int lane = threadIdx.x & 63;
    const int waveId = (blockIdx.x * blockDim.x + threadIdx.x) >> 6;
    const int nWaves = (gridDim.x * blockDim.x) >> 6;
    const float* __restrict__ W1 = weight + F * F;
    float w1c[F];
#pragma unroll
    for (int k = 0; k < F; ++k) w1c[k] = W1[k * F + lane];
    for (int n = waveId; n < n_nodes; n += nWaves) {
        const int nu = __builtin_amdgcn_readfirstlane(n);
        const float4* __restrict__ xr4 = (const float4*)(x_real + (size_t)nu * F);
        const float4* __restrict__ xi4 = (const float4*)(x_imag + (size_t)nu * F);
        float aR = 0.f, aI = 0.f;
#pragma unroll
        for (int k4 = 0; k4 < F / 4; ++k4) {
            const float4 vr = xr4[k4];
            const float4 vi = xi4[k4];
            const float xr[4] = {vr.x, vr.y, vr.z, vr.w};
            const float xi[4] = {vi.x, vi.y, vi.z, vi.w};
#pragma unroll
            for (int j = 0; j < 4; ++j) {
                const int k = 4 * k4 + j;
                aR = fmaf(xr[j], w1c[k], aR);
                aI = fmaf(xi[j], w1c[k], aI);
            }
        }
        x1p[(size_t)nu * F + lane] = pack_bf16x2(aR, aI);
    }
}

__global__ __launch_bounds__(256) void k_scatter(
    const u32* __restrict__ x1p, const int* __restrict__ edge_index,
    const float* __restrict__ norm_real, const float* __restrict__ norm_imag,
    float* __restrict__ out_real, float* __restrict__ out_imag, int n_edges)
{
    const long long gid = (long long)blockIdx.x * blockDim.x + threadIdx.x;
    const long long total = (long long)n_edges * 16;
    if (gid >= total) return;
    const int e = (int)(gid >> 4);
    const int c = (int)(gid & 15);
    const int s = edge_index[e];
    const int d = edge_index[n_edges + e];
    const float cr = norm_real[e];
    const float ci = norm_imag[e];
    const uint4 p4 = *(const uint4*)(x1p + (size_t)d * F + c * 4);
    const u32 pp[4] = {p4.x, p4.y, p4.z, p4.w};
    float* __restrict__ pr = out_real + (size_t)s * F + c * 4;
    float* __restrict__ pi = out_imag + (size_t)s * F + c * 4;
#pragma unroll
    for (int j = 0; j < 4; ++j) {
        const float xr = unpack_lo(pp[j]);
        const float xi = unpack_hi(pp[j]);
        unsafeAtomicAdd(pr + j, fmaf(cr, xr, -ci * xi));
        unsafeAtomicAdd(pi + j, fmaf(cr, xi, ci * xr));
    }
}

extern "C" void kernel_launch(void* const* d_in, const int* in_sizes, int n_in,
                              void* d_out, int out_size, void* d_ws, size_t ws_size,
                              hipStream_t stream) {
    const float* x_real     = (const float*)d_in[0];
    const float* x_imag     = (const float*)d_in[1];
    const float* weight     = (const float*)d_in[2];
    const float* bias       = (const float*)d_in[3];
    const float* norm_real  = (const float*)d_in[4];
    const float* norm_imag  = (const float*)d_in[5];
    const int*   edge_index = (const int*)d_in[6];

    const int n_nodes = in_sizes[0] / F;
    const int n_edges = in_sizes[4];

    float* out_real = (float*)d_out;
    float* out_imag = out_real + (size_t)n_nodes * F;
    u32*   initp    = (u32*)d_out;   // packed bf16 init, overwritten by gather

    // ws layout: [x1p][meta2][offsets][cursor][partials]
    char* ws = (char*)d_ws;
    const size_t x1_bytes   = (size_t)n_nodes * F * sizeof(u32);   // 25.6 MB
    const size_t meta_bytes = (size_t)n_edges * sizeof(u64);       // 12.8 MB
    const size_t off_bytes  = (size_t)(n_nodes + 1) * sizeof(int);
    const size_t cur_bytes  = (size_t)n_nodes * sizeof(int);
    const size_t par_bytes  = 64 * sizeof(int);
    const size_t need = x1_bytes + meta_bytes + off_bytes + cur_bytes + par_bytes;

    u32*  x1p      = (u32*)ws;
    u64*  meta2    = (u64*)(ws + x1_bytes);
    int*  offsets  = (int*)(ws + x1_bytes + meta_bytes);
    int*  cursor   = (int*)(ws + x1_bytes + meta_bytes + off_bytes);
    int*  partials = (int*)(ws + x1_bytes + meta_bytes + off_bytes + cur_bytes);

    if (ws_size >= need) {
        (void)hipMemsetAsync(cursor, 0, cur_bytes, stream);
        const int gblocks = (n_nodes + 63) / 64;
        k_gemm<<<gblocks, 256, 0, stream>>>(
            x_real, x_imag, weight, bias, x1p, initp, edge_index, cursor,
            n_nodes, n_edges);
        const int sblocks = (n_nodes + SCAN_BLOCK * SCAN_ITEMS - 1) / (SCAN_BLOCK * SCAN_ITEMS);
        k_scan1<<<sblocks, SCAN_BLOCK, 0, stream>>>(cursor, offsets, partials, n_nodes);
        k_scan2<<<sblocks, SCAN_BLOCK, 0, stream>>>(offsets, partials, cursor, n_nodes, n_edges);
        k_place<<<2048, 256, 0, stream>>>(edge_index, norm_real, norm_imag,
                                          cursor, meta2, n_edges, n_nodes);
        k_gather<<<2048, 256, 0, stream>>>(
            x1p, initp, offsets, meta2, out_real, out_imag, n_nodes);
    } else {
        k_init_out<<<2048, 256, 0, stream>>>(
            x_real, x_imag, weight, bias, out_real, out_imag, n_nodes);
        k_x1_only<<<2048, 256, 0, stream>>>(x_real, x_imag, weight, x1p, n_nodes);
        const long long work = (long long)n_edges * 16;
        const int blocks = (int)((work + 255) / 256);
        k_scatter<<<blocks, 256, 0, stream>>>(
            x1p, edge_index, norm_real, norm_imag, out_real, out_imag, n_edges);
    }
}